// Round 7
// baseline (251.729 us; speedup 1.0000x reference)
//
#include <hip/hip_runtime.h>
#include <hip/hip_bf16.h>
#include <string.h>

#define D 256
#define NH 8
#define DH 32
#define NL 4
#define NP 4
#define DFF 1024
#define LTOT 8500

typedef __bf16 bf16x8 __attribute__((ext_vector_type(8)));
typedef float floatx4 __attribute__((ext_vector_type(4)));

__device__ inline unsigned bpack(float a, float b) {
    __hip_bfloat16 ha = __float2bfloat16(a), hb = __float2bfloat16(b);
    unsigned short ua, ub;
    memcpy(&ua, &ha, 2); memcpy(&ub, &hb, 2);
    return (unsigned)ua | ((unsigned)ub << 16);
}

// ---------------- transpose+convert 6 weights, exact 736-tile grid ----------------
__global__ void transpose_all(const float* W0, const float* W1_, const float* W2_,
                              const float* W3, const float* W4, const float* W5,
                              __hip_bfloat16* T0, __hip_bfloat16* T1, __hip_bfloat16* T2,
                              __hip_bfloat16* T3, __hip_bfloat16* T4, __hip_bfloat16* T5) {
    const int cum[7] = {0, 64, 96, 160, 224, 480, 736};
    int id = blockIdx.x;
    int mi = 0;
    while (id >= cum[mi + 1]) mi++;
    int lid = id - cum[mi];
    const float* W; __hip_bfloat16* T; int K, N;
    switch (mi) {
        case 0: W = W0; T = T0; K = 256;  N = 256;  break;
        case 1: W = W1_; T = T1; K = 256; N = 128;  break;
        case 2: W = W2_; T = T2; K = 256; N = 256;  break;
        case 3: W = W3; T = T3; K = 256;  N = 256;  break;
        case 4: W = W4; T = T4; K = 256;  N = 1024; break;
        default: W = W5; T = T5; K = 1024; N = 256; break;
    }
    int ntx = N >> 5;
    int n0 = (lid % ntx) * 32, k0 = (lid / ntx) * 32;
    __shared__ float t[32][33];
    int tx = threadIdx.x & 31, ty = threadIdx.x >> 5;
#pragma unroll
    for (int i = 0; i < 32; i += 8)
        t[ty + i][tx] = W[(size_t)(k0 + ty + i) * N + n0 + tx];
    __syncthreads();
#pragma unroll
    for (int i = 0; i < 32; i += 8)
        T[(size_t)(n0 + ty + i) * K + k0 + tx] = __float2bfloat16(t[tx][ty + i]);
}

// ---------------- fused projection GEMM: [Wo | Wa | Wv], N=640, BN=128, fp32 A with cvt ----------------
__global__ __launch_bounds__(256) void proj_fused(
    const float* __restrict__ src, const float* __restrict__ pos,
    const __hip_bfloat16* __restrict__ WoT, const __hip_bfloat16* __restrict__ WaT,
    const __hip_bfloat16* __restrict__ WvT,
    const float* __restrict__ bo, const float* __restrict__ ba, const float* __restrict__ bv,
    float* __restrict__ locb, float* __restrict__ attnb, __hip_bfloat16* __restrict__ valb,
    int M) {
    constexpr int BM = 64, BN = 128, BK = 32, K = 256;
    constexpr int LDA = BK + 8;
    __shared__ __align__(16) __hip_bfloat16 sA[BM * LDA];
    __shared__ __align__(16) __hip_bfloat16 sB[BN * LDA];

    int n0 = blockIdx.x * BN;
    int m0 = blockIdx.y * BM;

    const __hip_bfloat16* BT;
    const float* bias;
    int ncol0, Nout, usePos;
    float* Cf; __hip_bfloat16* Cb;
    if (n0 < 256)      { BT = WoT; bias = bo; ncol0 = n0;       Nout = 256; Cf = locb;  Cb = nullptr; usePos = 1; }
    else if (n0 < 384) { BT = WaT; bias = ba; ncol0 = n0 - 256; Nout = 128; Cf = attnb; Cb = nullptr; usePos = 1; }
    else               { BT = WvT; bias = bv; ncol0 = n0 - 384; Nout = 256; Cf = nullptr; Cb = valb; usePos = 0; }

    int tid = threadIdx.x;
    int wave = tid >> 6, lane = tid & 63;
    int wm = (wave >> 1) * 32;        // 2x2 wave grid: 32 rows x 64 cols each
    int wn = (wave & 1) * 64;

    floatx4 acc[2][4];
#pragma unroll
    for (int i = 0; i < 2; i++)
#pragma unroll
        for (int j = 0; j < 4; j++)
#pragma unroll
            for (int e = 0; e < 4; e++) acc[i][j][e] = 0.f;

    int rowT = tid >> 2, c16 = tid & 3;
    int lrow = lane & 15, lk = (lane >> 4) * 8;

    for (int k0 = 0; k0 < K; k0 += BK) {
        {
            int grow = m0 + rowT; if (grow >= M) grow = M - 1;
            const float* ap = src + (size_t)grow * K + k0 + c16 * 8;
            float4 s0 = *(const float4*)ap;
            float4 s1 = *(const float4*)(ap + 4);
            if (usePos) {
                const float* pp = pos + (size_t)grow * K + k0 + c16 * 8;
                float4 p0 = *(const float4*)pp;
                float4 p1 = *(const float4*)(pp + 4);
                s0.x += p0.x; s0.y += p0.y; s0.z += p0.z; s0.w += p0.w;
                s1.x += p1.x; s1.y += p1.y; s1.z += p1.z; s1.w += p1.w;
            }
            uint4 pk;
            pk.x = bpack(s0.x, s0.y); pk.y = bpack(s0.z, s0.w);
            pk.z = bpack(s1.x, s1.y); pk.w = bpack(s1.z, s1.w);
            *(uint4*)(&sA[rowT * LDA + c16 * 8]) = pk;
#pragma unroll
            for (int r = 0; r < 2; r++) {
                int brow = r * 64 + rowT;
                *(bf16x8*)(&sB[brow * LDA + c16 * 8]) =
                    *(const bf16x8*)(BT + (size_t)(ncol0 + brow) * K + k0 + c16 * 8);
            }
        }
        __syncthreads();
        bf16x8 af[2], bfr[4];
#pragma unroll
        for (int t = 0; t < 2; t++)
            af[t] = *(const bf16x8*)(&sA[(wm + t * 16 + lrow) * LDA + lk]);
#pragma unroll
        for (int t = 0; t < 4; t++)
            bfr[t] = *(const bf16x8*)(&sB[(wn + t * 16 + lrow) * LDA + lk]);
#pragma unroll
        for (int tm = 0; tm < 2; tm++)
#pragma unroll
            for (int tn = 0; tn < 4; tn++)
                acc[tm][tn] = __builtin_amdgcn_mfma_f32_16x16x32_bf16(af[tm], bfr[tn], acc[tm][tn], 0, 0, 0);
        __syncthreads();
    }

    int lcol = lane & 15, lr4 = (lane >> 4) * 4;
#pragma unroll
    for (int tm = 0; tm < 2; tm++) {
#pragma unroll
        for (int i = 0; i < 4; i++) {
            int row = m0 + wm + tm * 16 + lr4 + i;
            if (row < M) {
#pragma unroll
                for (int tn = 0; tn < 4; tn++) {
                    int col = ncol0 + wn + tn * 16 + lcol;
                    float v = acc[tm][tn][i] + bias[col];
                    if (Cf) Cf[(size_t)row * Nout + col] = v;
                    else    Cb[(size_t)row * Nout + col] = __float2bfloat16(v);
                }
            }
        }
    }
}

// ---------------- deform core: softmax+loc fused, 4 queries/block, 8 lanes/(q,h) ----------------
__global__ __launch_bounds__(256) void deform(const __hip_bfloat16* __restrict__ value,
                                              const float* __restrict__ locraw,
                                              const float* __restrict__ logits,
                                              const float* __restrict__ refp,
                                              __hip_bfloat16* __restrict__ out) {
    __shared__ float wS[4][8][16][4];
    __shared__ int   aS[4][8][16][4];
    int tid = threadIdx.x;
    int q0 = blockIdx.x * 4;

    {   // phase 1
        int sub = tid >> 6, h = (tid >> 3) & 7, t8 = tid & 7;
        int q = q0 + sub;
        const float* lg = logits + q * 128 + h * 16;
        float l0 = lg[t8], l1 = lg[t8 + 8];
        float mx = fmaxf(l0, l1);
#pragma unroll
        for (int m = 1; m < 8; m <<= 1) mx = fmaxf(mx, __shfl_xor(mx, m, 64));
        float e0 = __expf(l0 - mx), e1 = __expf(l1 - mx);
        float s = e0 + e1;
#pragma unroll
        for (int m = 1; m < 8; m <<= 1) s += __shfl_xor(s, m, 64);
        float inv = 1.f / s;

        const int starts[4] = {0, 6400, 8000, 8400};
#pragma unroll
        for (int j = 0; j < 2; j++) {
            int pp = t8 + 8 * j;
            float a = (j ? e1 : e0) * inv;
            int l = pp >> 2;
            int Wl = 80 >> l;
            float nv = (float)Wl;
            float rx = refp[q * 8 + l * 2 + 0];
            float ry = refp[q * 8 + l * 2 + 1];
            float lx = rx + locraw[q * 256 + h * 32 + pp * 2 + 0] / nv;
            float ly = ry + locraw[q * 256 + h * 32 + pp * 2 + 1] / nv;
            float x = lx * nv - 0.5f;
            float y = ly * nv - 0.5f;
            float x0f = floorf(x), y0f = floorf(y);
            float fx = x - x0f, fy = y - y0f;
            int x0 = (int)x0f, y0 = (int)y0f;
            float wts[4] = {(1.f - fx) * (1.f - fy), fx * (1.f - fy),
                            (1.f - fx) * fy,         fx * fy};
            int st = starts[l];
#pragma unroll
            for (int t = 0; t < 4; t++) {
                int xi = x0 + (t & 1), yi = y0 + (t >> 1);
                bool valid = (xi >= 0) & (xi < Wl) & (yi >= 0) & (yi < Wl);
                int xc = min(max(xi, 0), Wl - 1), yc = min(max(yi, 0), Wl - 1);
                wS[sub][h][pp][t] = valid ? wts[t] * a : 0.f;
                aS[sub][h][pp][t] = (st + yc * Wl + xc) * 512 + h * 64;
            }
        }
    }
    __syncthreads();

    // phase 2: tid = sub*64 + h*8 + l8
    int sub = tid >> 6, h = (tid >> 3) & 7, l8 = tid & 7;
    int q = q0 + sub;
    const char* vb = (const char*)value;
    int lo = l8 * 8;
    float a0 = 0.f, a1 = 0.f, a2 = 0.f, a3 = 0.f;
#pragma unroll
    for (int p = 0; p < 16; p++) {
        floatx4 w = *(const floatx4*)&wS[sub][h][p][0];
        int4 av = *(const int4*)&aS[sub][h][p][0];
#pragma unroll
        for (int t = 0; t < 4; t++) {
            int ad = (t == 0) ? av.x : (t == 1) ? av.y : (t == 2) ? av.z : av.w;
            uint2 u = *(const uint2*)(vb + ad + lo);
            float wt = w[t];
            a0 += wt * __uint_as_float(u.x << 16);
            a1 += wt * __uint_as_float(u.x & 0xffff0000u);
            a2 += wt * __uint_as_float(u.y << 16);
            a3 += wt * __uint_as_float(u.y & 0xffff0000u);
        }
    }
    uint2 o;
    o.x = bpack(a0, a1);
    o.y = bpack(a2, a3);
    *(uint2*)((char*)out + q * 512 + h * 64 + l8 * 8) = o;
}

// ---------------- GEMM (N=256) + bias + residual + LayerNorm fused; 512 threads ----------------
__global__ __launch_bounds__(512) void gemm_ln(
    const __hip_bfloat16* __restrict__ A, const __hip_bfloat16* __restrict__ BT,
    const float* __restrict__ bias, const float* __restrict__ resid,
    const float* __restrict__ g, const float* __restrict__ be,
    float* __restrict__ outf, __hip_bfloat16* __restrict__ outb,
    int M, int K) {
    constexpr int BM = 32, BK = 32, LDA = BK + 8;
    __shared__ __align__(16) __hip_bfloat16 sA[BM * LDA];
    __shared__ __align__(16) __hip_bfloat16 sB[256 * LDA];
    __shared__ float psum[8][32], psq[8][32], mS[32], rS[32];

    int tid = threadIdx.x;
    int wave = tid >> 6, lane = tid & 63;
    int m0 = blockIdx.x * BM;

    floatx4 acc[2][2];
#pragma unroll
    for (int i = 0; i < 2; i++)
#pragma unroll
        for (int j = 0; j < 2; j++)
#pragma unroll
            for (int e = 0; e < 4; e++) acc[i][j][e] = 0.f;

    int rowT = tid >> 2, c16 = tid & 3;     // rowT 0..127
    int lrow = lane & 15, lk = (lane >> 4) * 8;

    for (int k0 = 0; k0 < K; k0 += BK) {
        if (tid < 128) {
            int grow = m0 + rowT; if (grow >= M) grow = M - 1;
            *(bf16x8*)(&sA[rowT * LDA + c16 * 8]) =
                *(const bf16x8*)(A + (size_t)grow * K + k0 + c16 * 8);
        }
#pragma unroll
        for (int r = 0; r < 2; r++) {
            int row = r * 128 + rowT;
            *(bf16x8*)(&sB[row * LDA + c16 * 8]) =
                *(const bf16x8*)(BT + (size_t)row * K + k0 + c16 * 8);
        }
        __syncthreads();
        bf16x8 af[2], bfr[2];
#pragma unroll
        for (int tm = 0; tm < 2; tm++)
            af[tm] = *(const bf16x8*)(&sA[(tm * 16 + lrow) * LDA + lk]);
#pragma unroll
        for (int tn = 0; tn < 2; tn++)
            bfr[tn] = *(const bf16x8*)(&sB[(wave * 32 + tn * 16 + lrow) * LDA + lk]);
#pragma unroll
        for (int tm = 0; tm < 2; tm++)
#pragma unroll
            for (int tn = 0; tn < 2; tn++)
                acc[tm][tn] = __builtin_amdgcn_mfma_f32_16x16x32_bf16(af[tm], bfr[tn], acc[tm][tn], 0, 0, 0);
        __syncthreads();
    }

    int lcol = lane & 15, quad = lane >> 4;
    float v[2][2][4];
#pragma unroll
    for (int tm = 0; tm < 2; tm++) {
#pragma unroll
        for (int i = 0; i < 4; i++) {
            int row = tm * 16 + quad * 4 + i;
            int grow = m0 + row; if (grow >= M) grow = M - 1;
#pragma unroll
            for (int tn = 0; tn < 2; tn++) {
                int col = wave * 32 + tn * 16 + lcol;
                v[tm][tn][i] = acc[tm][tn][i] + bias[col] + resid[(size_t)grow * 256 + col];
            }
        }
    }

#pragma unroll
    for (int tm = 0; tm < 2; tm++) {
#pragma unroll
        for (int i = 0; i < 4; i++) {
            float s = 0.f, s2 = 0.f;
#pragma unroll
            for (int tn = 0; tn < 2; tn++) { float x = v[tm][tn][i]; s += x; s2 += x * x; }
#pragma unroll
            for (int m = 1; m < 16; m <<= 1) {
                s  += __shfl_xor(s, m, 64);
                s2 += __shfl_xor(s2, m, 64);
            }
            if (lcol == 0) {
                int row = tm * 16 + quad * 4 + i;
                psum[wave][row] = s;
                psq[wave][row]  = s2;
            }
        }
    }
    __syncthreads();
    if (tid < 32) {
        float s = 0.f, s2 = 0.f;
#pragma unroll
        for (int w = 0; w < 8; w++) { s += psum[w][tid]; s2 += psq[w][tid]; }
        float m = s * (1.f / 256.f);
        float var = fmaxf(s2 * (1.f / 256.f) - m * m, 0.f);
        mS[tid] = m;
        rS[tid] = rsqrtf(var + 1e-5f);
    }
    __syncthreads();

#pragma unroll
    for (int tm = 0; tm < 2; tm++) {
#pragma unroll
        for (int i = 0; i < 4; i++) {
            int row = tm * 16 + quad * 4 + i;
            int grow = m0 + row;
            if (grow < M) {
                float m = mS[row], r = rS[row];
#pragma unroll
                for (int tn = 0; tn < 2; tn++) {
                    int col = wave * 32 + tn * 16 + lcol;
                    float o = (v[tm][tn][i] - m) * r * g[col] + be[col];
                    outf[(size_t)grow * 256 + col] = o;
                    if (outb) outb[(size_t)grow * 256 + col] = __float2bfloat16(o);
                }
            }
        }
    }
}

// ---------------- fused FFN: out = LN(x1 + relu(x1b@W1+b1)@W2 + b2) ----------------
// BM=16 rows/block, 256 threads (4 waves). h kept in LDS; B-fragments straight from L2.
__global__ __launch_bounds__(256) void ffn_fused(
    const __hip_bfloat16* __restrict__ x1b, const float* __restrict__ x1,
    const __hip_bfloat16* __restrict__ W1T, const float* __restrict__ b1,
    const __hip_bfloat16* __restrict__ W2T, const float* __restrict__ b2,
    const float* __restrict__ g, const float* __restrict__ be,
    float* __restrict__ outf, int M) {
    constexpr int LDH = 1048;   // pad: row stride 2096 B -> <=2-way banks for b128 reads, 16B-aligned
    __shared__ __align__(16) __hip_bfloat16 sA[16 * 264];
    __shared__ __align__(16) __hip_bfloat16 sH[16 * LDH];
    __shared__ float psum[4][16], psq[4][16], mS[16], rS[16];

    int tid = threadIdx.x;
    int wave = tid >> 6, lane = tid & 63;
    int m0 = blockIdx.x * 16;
    int lrow = lane & 15, quad = lane >> 4;
    int lk = quad * 8;

    // load A tile: 16 rows x 256 cols bf16; 512 chunks of 8, 2 per thread
    {
        int ch = tid;
#pragma unroll
        for (int r = 0; r < 2; r++, ch += 256) {
            int row = ch >> 5, col = (ch & 31) * 8;
            int grow = m0 + row; if (grow >= M) grow = M - 1;
            *(bf16x8*)(&sA[row * 264 + col]) = *(const bf16x8*)(x1b + (size_t)grow * 256 + col);
        }
    }
    __syncthreads();

    // GEMM1: h = relu(A @ W1 + b1); wave w covers h cols [w*256, w*256+256)
#pragma unroll
    for (int np = 0; np < 4; np++) {
        int nbase = wave * 256 + np * 64;
        floatx4 acc[4];
#pragma unroll
        for (int j = 0; j < 4; j++)
#pragma unroll
            for (int e = 0; e < 4; e++) acc[j][e] = 0.f;
#pragma unroll
        for (int k0 = 0; k0 < 256; k0 += 32) {
            bf16x8 af = *(const bf16x8*)(&sA[lrow * 264 + k0 + lk]);
#pragma unroll
            for (int j = 0; j < 4; j++) {
                bf16x8 bfb = *(const bf16x8*)(W1T + (size_t)(nbase + j * 16 + lrow) * 256 + k0 + lk);
                acc[j] = __builtin_amdgcn_mfma_f32_16x16x32_bf16(af, bfb, acc[j], 0, 0, 0);
            }
        }
#pragma unroll
        for (int j = 0; j < 4; j++) {
            int col = nbase + j * 16 + lrow;
            float bb = b1[col];
#pragma unroll
            for (int i = 0; i < 4; i++) {
                int row = quad * 4 + i;
                float hv = fmaxf(acc[j][i] + bb, 0.f);
                sH[row * LDH + col] = __float2bfloat16(hv);
            }
        }
    }
    __syncthreads();

    // GEMM2: o = h @ W2 + b2; wave w covers out cols [w*64, w*64+64)
    floatx4 acc2[4];
#pragma unroll
    for (int j = 0; j < 4; j++)
#pragma unroll
        for (int e = 0; e < 4; e++) acc2[j][e] = 0.f;
    for (int k0 = 0; k0 < 1024; k0 += 32) {
        bf16x8 af = *(const bf16x8*)(&sH[lrow * LDH + k0 + lk]);
#pragma unroll
        for (int j = 0; j < 4; j++) {
            bf16x8 bfb = *(const bf16x8*)(W2T + (size_t)(wave * 64 + j * 16 + lrow) * 1024 + k0 + lk);
            acc2[j] = __builtin_amdgcn_mfma_f32_16x16x32_bf16(af, bfb, acc2[j], 0, 0, 0);
        }
    }

    // epilogue: bias + residual + LN over 256 cols
    float v[4][4];
#pragma unroll
    for (int j = 0; j < 4; j++) {
        int col = wave * 64 + j * 16 + lrow;
        float bb = b2[col];
#pragma unroll
        for (int i = 0; i < 4; i++) {
            int row = quad * 4 + i;
            int grow = m0 + row; if (grow >= M) grow = M - 1;
            v[j][i] = acc2[j][i] + bb + x1[(size_t)grow * 256 + col];
        }
    }
#pragma unroll
    for (int i = 0; i < 4; i++) {
        float s = 0.f, s2 = 0.f;
#pragma unroll
        for (int j = 0; j < 4; j++) { float x = v[j][i]; s += x; s2 += x * x; }
#pragma unroll
        for (int m = 1; m < 16; m <<= 1) {
            s  += __shfl_xor(s, m, 64);
            s2 += __shfl_xor(s2, m, 64);
        }
        if (lrow == 0) {
            int row = quad * 4 + i;
            psum[wave][row] = s;
            psq[wave][row]  = s2;
        }
    }
    __syncthreads();
    if (tid < 16) {
        float s = 0.f, s2 = 0.f;
#pragma unroll
        for (int w = 0; w < 4; w++) { s += psum[w][tid]; s2 += psq[w][tid]; }
        float m = s * (1.f / 256.f);
        float var = fmaxf(s2 * (1.f / 256.f) - m * m, 0.f);
        mS[tid] = m;
        rS[tid] = rsqrtf(var + 1e-5f);
    }
    __syncthreads();
#pragma unroll
    for (int i = 0; i < 4; i++) {
        int row = quad * 4 + i;
        int grow = m0 + row;
        if (grow < M) {
            float m = mS[row], r = rS[row];
#pragma unroll
            for (int j = 0; j < 4; j++) {
                int col = wave * 64 + j * 16 + lrow;
                outf[(size_t)grow * 256 + col] = (v[j][i] - m) * r * g[col] + be[col];
            }
        }
    }
}

extern "C" void kernel_launch(void* const* d_in, const int* in_sizes, int n_in,
                              void* d_out, int out_size, void* d_ws, size_t ws_size,
                              hipStream_t stream) {
    const float* src  = (const float*)d_in[0];
    const float* pos  = (const float*)d_in[1];
    const float* refp = (const float*)d_in[2];
    const float* Wo   = (const float*)d_in[6];
    const float* bo   = (const float*)d_in[7];
    const float* Wa   = (const float*)d_in[8];
    const float* ba   = (const float*)d_in[9];
    const float* Wv   = (const float*)d_in[10];
    const float* bv   = (const float*)d_in[11];
    const float* Wout = (const float*)d_in[12];
    const float* bout = (const float*)d_in[13];
    const float* W1   = (const float*)d_in[14];
    const float* b1   = (const float*)d_in[15];
    const float* W2   = (const float*)d_in[16];
    const float* b2   = (const float*)d_in[17];
    const float* g1   = (const float*)d_in[18];
    const float* be1  = (const float*)d_in[19];
    const float* g2   = (const float*)d_in[20];
    const float* be2  = (const float*)d_in[21];
    float* out = (float*)d_out;
    char* ws = (char*)d_ws;

    // ---- workspace layout (bytes) ----
    __hip_bfloat16* WoT   = (__hip_bfloat16*)(ws + 0);         //  131072
    __hip_bfloat16* WaT   = (__hip_bfloat16*)(ws + 131072);    //   65536
    __hip_bfloat16* WvT   = (__hip_bfloat16*)(ws + 196608);    //  131072
    __hip_bfloat16* WoutT = (__hip_bfloat16*)(ws + 327680);    //  131072
    __hip_bfloat16* W1T   = (__hip_bfloat16*)(ws + 458752);    //  524288
    __hip_bfloat16* W2T   = (__hip_bfloat16*)(ws + 983040);    //  524288
    float*          locb  = (float*)(ws + 1507328);            // 8704000
    float*          attnb = (float*)(ws + 10211328);           // 4352000
    __hip_bfloat16* valb  = (__hip_bfloat16*)(ws + 14563328);  // 4352000
    __hip_bfloat16* aob   = (__hip_bfloat16*)(ws + 18915328);  // 4352000
    float*          x1    = (float*)(ws + 23267328);           // 8704000
    __hip_bfloat16* x1b   = (__hip_bfloat16*)(ws + 31971328);  // 4352000  (end ~36.3 MB)

    transpose_all<<<736, 256, 0, stream>>>(Wo, Wa, Wv, Wout, W1, W2,
                                           WoT, WaT, WvT, WoutT, W1T, W2T);

    proj_fused<<<dim3(5, 133), 256, 0, stream>>>(src, pos, WoT, WaT, WvT, bo, ba, bv,
                                                 locb, attnb, valb, LTOT);

    deform<<<2125, 256, 0, stream>>>(valb, locb, attnb, refp, aob);

    gemm_ln<<<266, 512, 0, stream>>>(aob, WoutT, bout, src, g1, be1, x1, x1b, LTOT, 256);

    ffn_fused<<<532, 256, 0, stream>>>(x1b, x1, W1T, b1, W2T, b2, g2, be2, out, LTOT);
}

// Round 8
// 209.597 us; speedup vs baseline: 1.2010x; 1.2010x over previous
//
#include <hip/hip_runtime.h>
#include <hip/hip_bf16.h>
#include <string.h>

#define D 256
#define NH 8
#define DH 32
#define NL 4
#define NP 4
#define DFF 1024
#define LTOT 8500

typedef __bf16 bf16x8 __attribute__((ext_vector_type(8)));
typedef float floatx4 __attribute__((ext_vector_type(4)));

__device__ inline unsigned bpack(float a, float b) {
    __hip_bfloat16 ha = __float2bfloat16(a), hb = __float2bfloat16(b);
    unsigned short ua, ub;
    memcpy(&ua, &ha, 2); memcpy(&ub, &hb, 2);
    return (unsigned)ua | ((unsigned)ub << 16);
}

// ---------------- transpose+convert 6 weights, exact 736-tile grid ----------------
__global__ void transpose_all(const float* W0, const float* W1_, const float* W2_,
                              const float* W3, const float* W4, const float* W5,
                              __hip_bfloat16* T0, __hip_bfloat16* T1, __hip_bfloat16* T2,
                              __hip_bfloat16* T3, __hip_bfloat16* T4, __hip_bfloat16* T5) {
    const int cum[7] = {0, 64, 96, 160, 224, 480, 736};
    int id = blockIdx.x;
    int mi = 0;
    while (id >= cum[mi + 1]) mi++;
    int lid = id - cum[mi];
    const float* W; __hip_bfloat16* T; int K, N;
    switch (mi) {
        case 0: W = W0; T = T0; K = 256;  N = 256;  break;
        case 1: W = W1_; T = T1; K = 256; N = 128;  break;
        case 2: W = W2_; T = T2; K = 256; N = 256;  break;
        case 3: W = W3; T = T3; K = 256;  N = 256;  break;
        case 4: W = W4; T = T4; K = 256;  N = 1024; break;
        default: W = W5; T = T5; K = 1024; N = 256; break;
    }
    int ntx = N >> 5;
    int n0 = (lid % ntx) * 32, k0 = (lid / ntx) * 32;
    __shared__ float t[32][33];
    int tx = threadIdx.x & 31, ty = threadIdx.x >> 5;
#pragma unroll
    for (int i = 0; i < 32; i += 8)
        t[ty + i][tx] = W[(size_t)(k0 + ty + i) * N + n0 + tx];
    __syncthreads();
#pragma unroll
    for (int i = 0; i < 32; i += 8)
        T[(size_t)(n0 + ty + i) * K + k0 + tx] = __float2bfloat16(t[tx][ty + i]);
}

// ---------------- generic bf16 MFMA GEMM with register-prefetch dbuf ----------------
template<int BM, int BN>
__global__ __launch_bounds__(256) void gemm_mfma(
    const __hip_bfloat16* __restrict__ A, const __hip_bfloat16* __restrict__ BT,
    const float* __restrict__ bias, float* __restrict__ Cf, __hip_bfloat16* __restrict__ Cb,
    int M, int N, int K, int relu) {
    constexpr int BK = 32;
    constexpr int LDA = BK + 8;
    __shared__ __align__(16) __hip_bfloat16 sA[BM * LDA];
    __shared__ __align__(16) __hip_bfloat16 sB[BN * LDA];

    int tid = threadIdx.x;
    int wave = tid >> 6, lane = tid & 63;
    int m0 = blockIdx.y * BM;
    int n0 = blockIdx.x * BN;
    constexpr int WM = BM / 2, WN = BN / 2;
    int wm = (wave >> 1) * WM;
    int wn = (wave & 1) * WN;
    constexpr int TM = WM / 16, TN = WN / 16;

    floatx4 acc[TM][TN];
#pragma unroll
    for (int i = 0; i < TM; i++)
#pragma unroll
        for (int j = 0; j < TN; j++)
#pragma unroll
            for (int e = 0; e < 4; e++) acc[i][j][e] = 0.f;

    constexpr int RA = BM / 64, RB = BN / 64;
    int rowT = tid >> 2;
    int c16 = tid & 3;
    int lrow = lane & 15;
    int lk = (lane >> 4) * 8;

    int growA[RA];
#pragma unroll
    for (int r = 0; r < RA; r++) {
        int g = m0 + r * 64 + rowT; if (g >= M) g = M - 1;
        growA[r] = g;
    }

    bf16x8 pa[RA], pb[RB];
#pragma unroll
    for (int r = 0; r < RA; r++)
        pa[r] = *(const bf16x8*)(A + (size_t)growA[r] * K + c16 * 8);
#pragma unroll
    for (int r = 0; r < RB; r++)
        pb[r] = *(const bf16x8*)(BT + (size_t)(n0 + r * 64 + rowT) * K + c16 * 8);

    for (int k0 = 0; k0 < K; k0 += BK) {
#pragma unroll
        for (int r = 0; r < RA; r++)
            *(bf16x8*)(&sA[(r * 64 + rowT) * LDA + c16 * 8]) = pa[r];
#pragma unroll
        for (int r = 0; r < RB; r++)
            *(bf16x8*)(&sB[(r * 64 + rowT) * LDA + c16 * 8]) = pb[r];
        __syncthreads();

        int kn = k0 + BK;
        if (kn < K) {
#pragma unroll
            for (int r = 0; r < RA; r++)
                pa[r] = *(const bf16x8*)(A + (size_t)growA[r] * K + kn + c16 * 8);
#pragma unroll
            for (int r = 0; r < RB; r++)
                pb[r] = *(const bf16x8*)(BT + (size_t)(n0 + r * 64 + rowT) * K + kn + c16 * 8);
        }

        bf16x8 af[TM], bfr[TN];
#pragma unroll
        for (int tm = 0; tm < TM; tm++)
            af[tm] = *(const bf16x8*)(&sA[(wm + tm * 16 + lrow) * LDA + lk]);
#pragma unroll
        for (int tn = 0; tn < TN; tn++)
            bfr[tn] = *(const bf16x8*)(&sB[(wn + tn * 16 + lrow) * LDA + lk]);
#pragma unroll
        for (int tm = 0; tm < TM; tm++)
#pragma unroll
            for (int tn = 0; tn < TN; tn++)
                acc[tm][tn] = __builtin_amdgcn_mfma_f32_16x16x32_bf16(af[tm], bfr[tn], acc[tm][tn], 0, 0, 0);
        __syncthreads();
    }

    int lcol = lane & 15;
    int lr4 = (lane >> 4) * 4;
#pragma unroll
    for (int tm = 0; tm < TM; tm++) {
#pragma unroll
        for (int i = 0; i < 4; i++) {
            int row = m0 + wm + tm * 16 + lr4 + i;
            if (row < M) {
#pragma unroll
                for (int tn = 0; tn < TN; tn++) {
                    int col = n0 + wn + tn * 16 + lcol;
                    float v = acc[tm][tn][i] + bias[col];
                    if (relu) v = fmaxf(v, 0.f);
                    if (Cf) Cf[(size_t)row * N + col] = v;
                    if (Cb) Cb[(size_t)row * N + col] = __float2bfloat16(v);
                }
            }
        }
    }
}

// ---------------- fused projection GEMM: [Wo | Wa | Wv], N=640, BN=128, prefetch dbuf ----------------
__global__ __launch_bounds__(256) void proj_fused(
    const float* __restrict__ src, const float* __restrict__ pos,
    const __hip_bfloat16* __restrict__ WoT, const __hip_bfloat16* __restrict__ WaT,
    const __hip_bfloat16* __restrict__ WvT,
    const float* __restrict__ bo, const float* __restrict__ ba, const float* __restrict__ bv,
    float* __restrict__ locb, float* __restrict__ attnb, __hip_bfloat16* __restrict__ valb,
    int M) {
    constexpr int BM = 64, BN = 128, BK = 32, K = 256;
    constexpr int LDA = BK + 8;
    __shared__ __align__(16) __hip_bfloat16 sA[BM * LDA];
    __shared__ __align__(16) __hip_bfloat16 sB[BN * LDA];

    int n0 = blockIdx.x * BN;
    int m0 = blockIdx.y * BM;

    const __hip_bfloat16* BT;
    const float* bias;
    int ncol0, Nout, usePos;
    float* Cf; __hip_bfloat16* Cb;
    if (n0 < 256)      { BT = WoT; bias = bo; ncol0 = n0;       Nout = 256; Cf = locb;  Cb = nullptr; usePos = 1; }
    else if (n0 < 384) { BT = WaT; bias = ba; ncol0 = n0 - 256; Nout = 128; Cf = attnb; Cb = nullptr; usePos = 1; }
    else               { BT = WvT; bias = bv; ncol0 = n0 - 384; Nout = 256; Cf = nullptr; Cb = valb; usePos = 0; }

    int tid = threadIdx.x;
    int wave = tid >> 6, lane = tid & 63;
    int wm = (wave >> 1) * 32;
    int wn = (wave & 1) * 64;

    floatx4 acc[2][4];
#pragma unroll
    for (int i = 0; i < 2; i++)
#pragma unroll
        for (int j = 0; j < 4; j++)
#pragma unroll
            for (int e = 0; e < 4; e++) acc[i][j][e] = 0.f;

    int rowT = tid >> 2, c16 = tid & 3;
    int lrow = lane & 15, lk = (lane >> 4) * 8;

    int growA = m0 + rowT; if (growA >= M) growA = M - 1;
    const float* aBase = src + (size_t)growA * K + c16 * 8;
    const float* pBase = pos + (size_t)growA * K + c16 * 8;

    float4 s0, s1, p0, p1;
    bf16x8 pb[2];
    {
        s0 = *(const float4*)aBase;
        s1 = *(const float4*)(aBase + 4);
        if (usePos) { p0 = *(const float4*)pBase; p1 = *(const float4*)(pBase + 4); }
#pragma unroll
        for (int r = 0; r < 2; r++)
            pb[r] = *(const bf16x8*)(BT + (size_t)(ncol0 + r * 64 + rowT) * K + c16 * 8);
    }

    for (int k0 = 0; k0 < K; k0 += BK) {
        {
            float4 a0 = s0, a1 = s1;
            if (usePos) {
                a0.x += p0.x; a0.y += p0.y; a0.z += p0.z; a0.w += p0.w;
                a1.x += p1.x; a1.y += p1.y; a1.z += p1.z; a1.w += p1.w;
            }
            uint4 pk;
            pk.x = bpack(a0.x, a0.y); pk.y = bpack(a0.z, a0.w);
            pk.z = bpack(a1.x, a1.y); pk.w = bpack(a1.z, a1.w);
            *(uint4*)(&sA[rowT * LDA + c16 * 8]) = pk;
#pragma unroll
            for (int r = 0; r < 2; r++)
                *(bf16x8*)(&sB[(r * 64 + rowT) * LDA + c16 * 8]) = pb[r];
        }
        __syncthreads();

        int kn = k0 + BK;
        if (kn < K) {
            s0 = *(const float4*)(aBase + kn);
            s1 = *(const float4*)(aBase + kn + 4);
            if (usePos) {
                p0 = *(const float4*)(pBase + kn);
                p1 = *(const float4*)(pBase + kn + 4);
            }
#pragma unroll
            for (int r = 0; r < 2; r++)
                pb[r] = *(const bf16x8*)(BT + (size_t)(ncol0 + r * 64 + rowT) * K + kn + c16 * 8);
        }

        bf16x8 af[2], bfr[4];
#pragma unroll
        for (int t = 0; t < 2; t++)
            af[t] = *(const bf16x8*)(&sA[(wm + t * 16 + lrow) * LDA + lk]);
#pragma unroll
        for (int t = 0; t < 4; t++)
            bfr[t] = *(const bf16x8*)(&sB[(wn + t * 16 + lrow) * LDA + lk]);
#pragma unroll
        for (int tm = 0; tm < 2; tm++)
#pragma unroll
            for (int tn = 0; tn < 4; tn++)
                acc[tm][tn] = __builtin_amdgcn_mfma_f32_16x16x32_bf16(af[tm], bfr[tn], acc[tm][tn], 0, 0, 0);
        __syncthreads();
    }

    int lcol = lane & 15, lr4 = (lane >> 4) * 4;
#pragma unroll
    for (int tm = 0; tm < 2; tm++) {
#pragma unroll
        for (int i = 0; i < 4; i++) {
            int row = m0 + wm + tm * 16 + lr4 + i;
            if (row < M) {
#pragma unroll
                for (int tn = 0; tn < 4; tn++) {
                    int col = ncol0 + wn + tn * 16 + lcol;
                    float v = acc[tm][tn][i] + bias[col];
                    if (Cf) Cf[(size_t)row * Nout + col] = v;
                    else    Cb[(size_t)row * Nout + col] = __float2bfloat16(v);
                }
            }
        }
    }
}

// ---------------- deform core: softmax+loc fused, 4 queries/block, 8 lanes/(q,h) ----------------
__global__ __launch_bounds__(256) void deform(const __hip_bfloat16* __restrict__ value,
                                              const float* __restrict__ locraw,
                                              const float* __restrict__ logits,
                                              const float* __restrict__ refp,
                                              __hip_bfloat16* __restrict__ out) {
    __shared__ float wS[4][8][16][4];
    __shared__ int   aS[4][8][16][4];
    int tid = threadIdx.x;
    int q0 = blockIdx.x * 4;

    {   // phase 1
        int sub = tid >> 6, h = (tid >> 3) & 7, t8 = tid & 7;
        int q = q0 + sub;
        const float* lg = logits + q * 128 + h * 16;
        float l0 = lg[t8], l1 = lg[t8 + 8];
        float mx = fmaxf(l0, l1);
#pragma unroll
        for (int m = 1; m < 8; m <<= 1) mx = fmaxf(mx, __shfl_xor(mx, m, 64));
        float e0 = __expf(l0 - mx), e1 = __expf(l1 - mx);
        float s = e0 + e1;
#pragma unroll
        for (int m = 1; m < 8; m <<= 1) s += __shfl_xor(s, m, 64);
        float inv = 1.f / s;

        const int starts[4] = {0, 6400, 8000, 8400};
#pragma unroll
        for (int j = 0; j < 2; j++) {
            int pp = t8 + 8 * j;
            float a = (j ? e1 : e0) * inv;
            int l = pp >> 2;
            int Wl = 80 >> l;
            float nv = (float)Wl;
            float rx = refp[q * 8 + l * 2 + 0];
            float ry = refp[q * 8 + l * 2 + 1];
            float lx = rx + locraw[q * 256 + h * 32 + pp * 2 + 0] / nv;
            float ly = ry + locraw[q * 256 + h * 32 + pp * 2 + 1] / nv;
            float x = lx * nv - 0.5f;
            float y = ly * nv - 0.5f;
            float x0f = floorf(x), y0f = floorf(y);
            float fx = x - x0f, fy = y - y0f;
            int x0 = (int)x0f, y0 = (int)y0f;
            float wts[4] = {(1.f - fx) * (1.f - fy), fx * (1.f - fy),
                            (1.f - fx) * fy,         fx * fy};
            int st = starts[l];
#pragma unroll
            for (int t = 0; t < 4; t++) {
                int xi = x0 + (t & 1), yi = y0 + (t >> 1);
                bool valid = (xi >= 0) & (xi < Wl) & (yi >= 0) & (yi < Wl);
                int xc = min(max(xi, 0), Wl - 1), yc = min(max(yi, 0), Wl - 1);
                wS[sub][h][pp][t] = valid ? wts[t] * a : 0.f;
                aS[sub][h][pp][t] = (st + yc * Wl + xc) * 512 + h * 64;
            }
        }
    }
    __syncthreads();

    // phase 2: tid = sub*64 + h*8 + l8
    int sub = tid >> 6, h = (tid >> 3) & 7, l8 = tid & 7;
    int q = q0 + sub;
    const char* vb = (const char*)value;
    int lo = l8 * 8;
    float a0 = 0.f, a1 = 0.f, a2 = 0.f, a3 = 0.f;
#pragma unroll
    for (int p = 0; p < 16; p++) {
        floatx4 w = *(const floatx4*)&wS[sub][h][p][0];
        int4 av = *(const int4*)&aS[sub][h][p][0];
#pragma unroll
        for (int t = 0; t < 4; t++) {
            int ad = (t == 0) ? av.x : (t == 1) ? av.y : (t == 2) ? av.z : av.w;
            uint2 u = *(const uint2*)(vb + ad + lo);
            float wt = w[t];
            a0 += wt * __uint_as_float(u.x << 16);
            a1 += wt * __uint_as_float(u.x & 0xffff0000u);
            a2 += wt * __uint_as_float(u.y << 16);
            a3 += wt * __uint_as_float(u.y & 0xffff0000u);
        }
    }
    uint2 o;
    o.x = bpack(a0, a1);
    o.y = bpack(a2, a3);
    *(uint2*)((char*)out + q * 512 + h * 64 + l8 * 8) = o;
}

// ---------------- GEMM (N=256) + bias + residual + LayerNorm fused; 512 thr, prefetch dbuf ----------------
__global__ __launch_bounds__(512) void gemm_ln(
    const __hip_bfloat16* __restrict__ A, const __hip_bfloat16* __restrict__ BT,
    const float* __restrict__ bias, const float* __restrict__ resid,
    const float* __restrict__ g, const float* __restrict__ be,
    float* __restrict__ outf, __hip_bfloat16* __restrict__ outb,
    int M, int K) {
    constexpr int BM = 32, BK = 32, LDA = BK + 8;
    __shared__ __align__(16) __hip_bfloat16 sA[BM * LDA];
    __shared__ __align__(16) __hip_bfloat16 sB[256 * LDA];
    __shared__ float psum[8][32], psq[8][32], mS[32], rS[32];

    int tid = threadIdx.x;
    int wave = tid >> 6, lane = tid & 63;
    int m0 = blockIdx.x * BM;

    floatx4 acc[2][2];
#pragma unroll
    for (int i = 0; i < 2; i++)
#pragma unroll
        for (int j = 0; j < 2; j++)
#pragma unroll
            for (int e = 0; e < 4; e++) acc[i][j][e] = 0.f;

    int rowT = tid >> 2, c16 = tid & 3;     // rowT 0..127
    int lrow = lane & 15, lk = (lane >> 4) * 8;

    int growA = m0 + rowT; if (growA >= M) growA = M - 1;   // valid for tid<128

    bf16x8 pA, pB[2];
    if (tid < 128)
        pA = *(const bf16x8*)(A + (size_t)growA * K + c16 * 8);
#pragma unroll
    for (int r = 0; r < 2; r++)
        pB[r] = *(const bf16x8*)(BT + (size_t)(r * 128 + rowT) * K + c16 * 8);

    for (int k0 = 0; k0 < K; k0 += BK) {
        if (tid < 128)
            *(bf16x8*)(&sA[rowT * LDA + c16 * 8]) = pA;
#pragma unroll
        for (int r = 0; r < 2; r++)
            *(bf16x8*)(&sB[(r * 128 + rowT) * LDA + c16 * 8]) = pB[r];
        __syncthreads();

        int kn = k0 + BK;
        if (kn < K) {
            if (tid < 128)
                pA = *(const bf16x8*)(A + (size_t)growA * K + kn + c16 * 8);
#pragma unroll
            for (int r = 0; r < 2; r++)
                pB[r] = *(const bf16x8*)(BT + (size_t)(r * 128 + rowT) * K + kn + c16 * 8);
        }

        bf16x8 af[2], bfr[2];
#pragma unroll
        for (int tm = 0; tm < 2; tm++)
            af[tm] = *(const bf16x8*)(&sA[(tm * 16 + lrow) * LDA + lk]);
#pragma unroll
        for (int tn = 0; tn < 2; tn++)
            bfr[tn] = *(const bf16x8*)(&sB[(wave * 32 + tn * 16 + lrow) * LDA + lk]);
#pragma unroll
        for (int tm = 0; tm < 2; tm++)
#pragma unroll
            for (int tn = 0; tn < 2; tn++)
                acc[tm][tn] = __builtin_amdgcn_mfma_f32_16x16x32_bf16(af[tm], bfr[tn], acc[tm][tn], 0, 0, 0);
        __syncthreads();
    }

    int lcol = lane & 15, quad = lane >> 4;
    float v[2][2][4];
#pragma unroll
    for (int tm = 0; tm < 2; tm++) {
#pragma unroll
        for (int i = 0; i < 4; i++) {
            int row = tm * 16 + quad * 4 + i;
            int grow = m0 + row; if (grow >= M) grow = M - 1;
#pragma unroll
            for (int tn = 0; tn < 2; tn++) {
                int col = wave * 32 + tn * 16 + lcol;
                v[tm][tn][i] = acc[tm][tn][i] + bias[col] + resid[(size_t)grow * 256 + col];
            }
        }
    }

#pragma unroll
    for (int tm = 0; tm < 2; tm++) {
#pragma unroll
        for (int i = 0; i < 4; i++) {
            float s = 0.f, s2 = 0.f;
#pragma unroll
            for (int tn = 0; tn < 2; tn++) { float x = v[tm][tn][i]; s += x; s2 += x * x; }
#pragma unroll
            for (int m = 1; m < 16; m <<= 1) {
                s  += __shfl_xor(s, m, 64);
                s2 += __shfl_xor(s2, m, 64);
            }
            if (lcol == 0) {
                int row = tm * 16 + quad * 4 + i;
                psum[wave][row] = s;
                psq[wave][row]  = s2;
            }
        }
    }
    __syncthreads();
    if (tid < 32) {
        float s = 0.f, s2 = 0.f;
#pragma unroll
        for (int w = 0; w < 8; w++) { s += psum[w][tid]; s2 += psq[w][tid]; }
        float m = s * (1.f / 256.f);
        float var = fmaxf(s2 * (1.f / 256.f) - m * m, 0.f);
        mS[tid] = m;
        rS[tid] = rsqrtf(var + 1e-5f);
    }
    __syncthreads();

#pragma unroll
    for (int tm = 0; tm < 2; tm++) {
#pragma unroll
        for (int i = 0; i < 4; i++) {
            int row = tm * 16 + quad * 4 + i;
            int grow = m0 + row;
            if (grow < M) {
                float m = mS[row], r = rS[row];
#pragma unroll
                for (int tn = 0; tn < 2; tn++) {
                    int col = wave * 32 + tn * 16 + lcol;
                    float o = (v[tm][tn][i] - m) * r * g[col] + be[col];
                    outf[(size_t)grow * 256 + col] = o;
                    if (outb) outb[(size_t)grow * 256 + col] = __float2bfloat16(o);
                }
            }
        }
    }
}

extern "C" void kernel_launch(void* const* d_in, const int* in_sizes, int n_in,
                              void* d_out, int out_size, void* d_ws, size_t ws_size,
                              hipStream_t stream) {
    const float* src  = (const float*)d_in[0];
    const float* pos  = (const float*)d_in[1];
    const float* refp = (const float*)d_in[2];
    const float* Wo   = (const float*)d_in[6];
    const float* bo   = (const float*)d_in[7];
    const float* Wa   = (const float*)d_in[8];
    const float* ba   = (const float*)d_in[9];
    const float* Wv   = (const float*)d_in[10];
    const float* bv   = (const float*)d_in[11];
    const float* Wout = (const float*)d_in[12];
    const float* bout = (const float*)d_in[13];
    const float* W1   = (const float*)d_in[14];
    const float* b1   = (const float*)d_in[15];
    const float* W2   = (const float*)d_in[16];
    const float* b2   = (const float*)d_in[17];
    const float* g1   = (const float*)d_in[18];
    const float* be1  = (const float*)d_in[19];
    const float* g2   = (const float*)d_in[20];
    const float* be2  = (const float*)d_in[21];
    float* out = (float*)d_out;
    char* ws = (char*)d_ws;

    // ---- workspace layout (bytes) ----
    __hip_bfloat16* WoT   = (__hip_bfloat16*)(ws + 0);         //  131072
    __hip_bfloat16* WaT   = (__hip_bfloat16*)(ws + 131072);    //   65536
    __hip_bfloat16* WvT   = (__hip_bfloat16*)(ws + 196608);    //  131072
    __hip_bfloat16* WoutT = (__hip_bfloat16*)(ws + 327680);    //  131072
    __hip_bfloat16* W1T   = (__hip_bfloat16*)(ws + 458752);    //  524288
    __hip_bfloat16* W2T   = (__hip_bfloat16*)(ws + 983040);    //  524288
    float*          locb  = (float*)(ws + 1507328);            // 8704000
    float*          attnb = (float*)(ws + 10211328);           // 4352000
    __hip_bfloat16* valb  = (__hip_bfloat16*)(ws + 14563328);  // 4352000
    __hip_bfloat16* aob   = (__hip_bfloat16*)(ws + 18915328);  // 4352000
    float*          x1    = (float*)(ws + 23267328);           // 8704000
    __hip_bfloat16* x1b   = (__hip_bfloat16*)(ws + 31971328);  // 4352000
    __hip_bfloat16* hb    = (__hip_bfloat16*)(ws + 36323328);  // 17408000  (end ~53.7 MB)

    transpose_all<<<736, 256, 0, stream>>>(Wo, Wa, Wv, Wout, W1, W2,
                                           WoT, WaT, WvT, WoutT, W1T, W2T);

    proj_fused<<<dim3(5, 133), 256, 0, stream>>>(src, pos, WoT, WaT, WvT, bo, ba, bv,
                                                 locb, attnb, valb, LTOT);

    deform<<<2125, 256, 0, stream>>>(valb, locb, attnb, refp, aob);

    gemm_ln<<<266, 512, 0, stream>>>(aob, WoutT, bout, src, g1, be1, x1, x1b, LTOT, 256);

    gemm_mfma<128, 128><<<dim3(8, 67), 256, 0, stream>>>(x1b, W1T, b1, nullptr, hb, LTOT, 1024, 256, 1);

    gemm_ln<<<266, 512, 0, stream>>>(hb, W2T, b2, x1, g2, be2, out, nullptr, LTOT, 1024);
}